// Round 8
// baseline (81.899 us; speedup 1.0000x reference)
//
#include <hip/hip_runtime.h>
#include <hip/hip_bf16.h>

// SpiralDeblock: B=8, N_IN=7056, N_UP=28224, SEQ=9, CIN=64, COUT=32
namespace {
constexpr int kB    = 8;
constexpr int kNIn  = 7056;
constexpr int kNUp  = 28224;
constexpr int kSeq  = 9;
constexpr int kCin  = 64;
constexpr int kCout = 32;
constexpr int kE    = 3 * kNUp;          // 84672
constexpr int kMRows = kB * kNUp;        // 225792
constexpr int kTilesPerB = kNUp / 16;    // 1764 (exact -> tiles never straddle batches)
constexpr int kWFragN = 18 * 2 * 64 * 8; // 18432 bf16 values (36,864 B)
constexpr int kCap   = 24;               // bucket capacity; P(overflow) ~ 6e-10 at Poisson(3)

// ws layout (bytes), 16B-aligned
constexpr size_t kOffPool   = 0;                          // bf16 pooled: 28,901,376
constexpr size_t kOffWfrag  = 28901376;                   // 36,864
constexpr size_t kOffCur    = kOffWfrag + 36864;          // 112,896
constexpr size_t kOffBucket = kOffCur + 112896;           // N_UP*24*8 = 5,419,008
}

typedef __attribute__((ext_vector_type(8))) short short8;
typedef __attribute__((ext_vector_type(4))) float f32x4;

__device__ __forceinline__ unsigned short f32_to_bf16(float f) {  // RNE
    unsigned int u = __float_as_uint(f);
    u += 0x7fffu + ((u >> 16) & 1u);
    return (unsigned short)(u >> 16);
}

// --- zero cursor (graph-safe, ~1 us) --------------------------------------
__global__ __launch_bounds__(256) void zero_kernel(int* __restrict__ cursor) {
    int i = blockIdx.x * 256 + threadIdx.x;
    if (i < kNUp) cursor[i] = 0;
}

// --- merged prep: blocks [0,72) transpose W to fragment order; blocks [72,...) bucket edges
__global__ __launch_bounds__(256) void prep_kernel(const float* __restrict__ W,
                                                   unsigned short* __restrict__ wfrag,
                                                   const int* __restrict__ row,
                                                   const int* __restrict__ col,
                                                   const float* __restrict__ val,
                                                   int* __restrict__ cursor,
                                                   uint2* __restrict__ bucket) {
    int bid = blockIdx.x;
    if (bid < kWFragN / 256) {
        int i  = bid * 256 + threadIdx.x;
        int j  = i & 7;
        int l  = (i >> 3) & 63;
        int ct = (i >> 9) & 1;
        int ks = i >> 10;                            // 0..17
        int k  = ks * 32 + (l >> 4) * 8 + j;
        int o  = ct * 16 + (l & 15);
        wfrag[i] = f32_to_bf16(W[k * kCout + o]);
    } else {
        int e = (bid - kWFragN / 256) * 256 + threadIdx.x;
        if (e >= kE) return;
        int r = row[e];
        int slot = atomicAdd(&cursor[r], 1);
        if ((unsigned)slot < (unsigned)kCap)
            bucket[(size_t)r * kCap + slot] = make_uint2((unsigned)col[e], __float_as_uint(val[e]));
    }
}

// --- pooled[b,r,c] = sum_{edges of r} x[b,col,c]*val, stored bf16 ---------
// thread = (r, c4): 16 lanes x float4 cover a 64-channel row; block = 16 rows.
// Per edge-pair: 16 independent float4 loads (256B in flight per lane) vs the
// old 4B scalar loads -- 4x fewer instructions, 4x MLP. Guards are per
// 16-lane group (quarter-wave divergence, exec-mask predicated).
__global__ __launch_bounds__(256) void pool_gather(const float* __restrict__ x,
                                                   const int* __restrict__ cursor,
                                                   const uint2* __restrict__ bucket,
                                                   unsigned short* __restrict__ poolb) {
    int t  = threadIdx.x;
    int c4 = t & 15;                                 // float4 chunk within row
    int r  = blockIdx.x * 16 + (t >> 4);             // < N_UP
    int n  = min(cursor[r], kCap);
    const uint2* bk = bucket + (size_t)r * kCap;
    const float* xc = x + (size_t)c4 * 4;

    f32x4 acc[kB];
#pragma unroll
    for (int b = 0; b < kB; ++b) acc[b] = (f32x4){0.f, 0.f, 0.f, 0.f};

#pragma unroll
    for (int p = 0; p < 4; ++p) {                    // pairs (0,1),(2,3),(4,5),(6,7)
        if (2 * p < n) {
            uint4 q = *reinterpret_cast<const uint4*>(bk + 2 * p);
            unsigned c0 = min(q.x, (unsigned)(kNIn - 1));
            float    v0 = __uint_as_float(q.y);
            unsigned c1 = min(q.z, (unsigned)(kNIn - 1));
            float    v1 = (2 * p + 1 < n) ? __uint_as_float(q.w) : 0.f;
            const float* x0 = xc + (size_t)c0 * kCin;
            const float* x1 = xc + (size_t)c1 * kCin;
            f32x4 xv0[kB], xv1[kB];
#pragma unroll
            for (int b = 0; b < kB; ++b) {           // 16 independent 16B loads
                xv0[b] = *reinterpret_cast<const f32x4*>(x0 + (size_t)b * kNIn * kCin);
                xv1[b] = *reinterpret_cast<const f32x4*>(x1 + (size_t)b * kNIn * kCin);
            }
#pragma unroll
            for (int b = 0; b < kB; ++b)
#pragma unroll
                for (int j = 0; j < 4; ++j)
                    acc[b][j] = fmaf(xv1[b][j], v1, fmaf(xv0[b][j], v0, acc[b][j]));
        }
    }
    for (int k = 8; k < n; ++k) {                    // rare tail (P ~ 0.4%)
        uint2 ev = bk[k];
        float v = __uint_as_float(ev.y);
        const float* xp = xc + (size_t)ev.x * kCin;
#pragma unroll
        for (int b = 0; b < kB; ++b) {
            f32x4 xv = *reinterpret_cast<const f32x4*>(xp + (size_t)b * kNIn * kCin);
#pragma unroll
            for (int j = 0; j < 4; ++j)
                acc[b][j] = fmaf(xv[j], v, acc[b][j]);
        }
    }
#pragma unroll
    for (int b = 0; b < kB; ++b) {
        ushort4 o;
        o.x = f32_to_bf16(acc[b][0]);
        o.y = f32_to_bf16(acc[b][1]);
        o.z = f32_to_bf16(acc[b][2]);
        o.w = f32_to_bf16(acc[b][3]);
        *reinterpret_cast<ushort4*>(poolb + ((size_t)b * kNUp + r) * kCin + c4 * 4) = o;
    }
}

// --- MFMA GEMM: out[R,o] = relu(sum_f spiral[R,f]*W[f,o] + bias[o]) -------
// 4 waves/block, 1 16-row M-tile per wave. W fragments staged in LDS (36,864 B,
// 4 blocks/CU). All 9 idx + 18 A-fragment loads issued BEFORE __syncthreads():
// barrier fence keeps them hoisted, vmcnt-drain hides latency under LDS fill.
// XCD chunk swizzle: 441 consecutive work-ids = one batch (3.6 MB < 4 MiB L2/XCD).
__global__ __launch_bounds__(256) void gemm_mfma(const unsigned short* __restrict__ poolb,
                                                 const unsigned short* __restrict__ wfrag,
                                                 const float* __restrict__ bias,
                                                 const int* __restrict__ indices,
                                                 float* __restrict__ out) {
    __shared__ short8 Bs[18 * 2 * 64];               // 2304 short8 = 36,864 B
    int t = threadIdx.x;
    const short8* wf = (const short8*)wfrag;
#pragma unroll
    for (int i = 0; i < 9; ++i)                      // coalesced b128 fill
        Bs[i * 256 + t] = wf[i * 256 + t];

    int l = t & 63;
    int w = t >> 6;
    int bid = blockIdx.x;
    int wk = (bid & 7) * (gridDim.x >> 3) + (bid >> 3);  // grid 3528 = 8*441
    int mtile = wk * 4 + w;
    int m  = l & 15;
    int kg = l >> 4;
    int b  = mtile / kTilesPerB;
    int nn = (mtile - b * kTilesPerB) * 16 + m;
    const unsigned short* pb = poolb + (size_t)b * kNUp * kCin;

    int idxs[kSeq];
#pragma unroll
    for (int s = 0; s < kSeq; ++s) idxs[s] = indices[nn * kSeq + s];

    short8 A0[kSeq], A1[kSeq];
#pragma unroll
    for (int s = 0; s < kSeq; ++s) {
        const short8* arow = (const short8*)(pb + (size_t)idxs[s] * kCin);
        A0[s] = arow[kg];                            // channels 0..31, this lane's 16B
        A1[s] = arow[4 + kg];                        // channels 32..63
    }
    float bs0 = bias[m];
    float bs1 = bias[16 + m];

    __syncthreads();                                 // Bs ready; A loads drained here

    f32x4 acc0 = {0.f, 0.f, 0.f, 0.f};
    f32x4 acc1 = {0.f, 0.f, 0.f, 0.f};
#pragma unroll
    for (int s = 0; s < kSeq; ++s) {
        short8 b00 = Bs[((s * 2 + 0) * 2 + 0) * 64 + l];
        short8 b01 = Bs[((s * 2 + 0) * 2 + 1) * 64 + l];
        short8 b10 = Bs[((s * 2 + 1) * 2 + 0) * 64 + l];
        short8 b11 = Bs[((s * 2 + 1) * 2 + 1) * 64 + l];
        acc0 = __builtin_amdgcn_mfma_f32_16x16x32_bf16(A0[s], b00, acc0, 0, 0, 0);
        acc1 = __builtin_amdgcn_mfma_f32_16x16x32_bf16(A0[s], b01, acc1, 0, 0, 0);
        acc0 = __builtin_amdgcn_mfma_f32_16x16x32_bf16(A1[s], b10, acc0, 0, 0, 0);
        acc1 = __builtin_amdgcn_mfma_f32_16x16x32_bf16(A1[s], b11, acc1, 0, 0, 0);
    }

    int orow0 = mtile * 16 + kg * 4;
#pragma unroll
    for (int r = 0; r < 4; ++r) {
        size_t orow = (size_t)(orow0 + r) * kCout;
        out[orow + m]      = fmaxf(acc0[r] + bs0, 0.f);
        out[orow + 16 + m] = fmaxf(acc1[r] + bs1, 0.f);
    }
}

extern "C" void kernel_launch(void* const* d_in, const int* in_sizes, int n_in,
                              void* d_out, int out_size, void* d_ws, size_t ws_size,
                              hipStream_t stream) {
    const float* x    = (const float*)d_in[0];
    const float* val  = (const float*)d_in[1];
    const float* W    = (const float*)d_in[2];
    const float* bias = (const float*)d_in[3];
    const int* row     = (const int*)d_in[4];
    const int* col     = (const int*)d_in[5];
    const int* indices = (const int*)d_in[6];
    float* out = (float*)d_out;

    char* wsb = (char*)d_ws;
    unsigned short* poolb = (unsigned short*)(wsb + kOffPool);
    unsigned short* wfrag = (unsigned short*)(wsb + kOffWfrag);
    int* cursor  = (int*)(wsb + kOffCur);
    uint2* bucket = (uint2*)(wsb + kOffBucket);

    zero_kernel<<<(kNUp + 255) / 256, 256, 0, stream>>>(cursor);

    constexpr int prep_blocks = kWFragN / 256 + (kE + 255) / 256;  // 72 + 331
    prep_kernel<<<prep_blocks, 256, 0, stream>>>(W, wfrag, row, col, val, cursor, bucket);

    pool_gather<<<kNUp / 16, 256, 0, stream>>>(x, cursor, bucket, poolb);

    gemm_mfma<<<(kMRows / 16) / 4, 256, 0, stream>>>(poolb, wfrag, bias, indices, out);
}

// Round 9
// 76.337 us; speedup vs baseline: 1.0729x; 1.0729x over previous
//
#include <hip/hip_runtime.h>
#include <hip/hip_bf16.h>

// SpiralDeblock: B=8, N_IN=7056, N_UP=28224, SEQ=9, CIN=64, COUT=32
namespace {
constexpr int kB    = 8;
constexpr int kNIn  = 7056;
constexpr int kNUp  = 28224;
constexpr int kSeq  = 9;
constexpr int kCin  = 64;
constexpr int kCout = 32;
constexpr int kE    = 3 * kNUp;          // 84672
constexpr int kMRows = kB * kNUp;        // 225792
constexpr int kTilesPerB = kNUp / 16;    // 1764 (exact -> tiles never straddle batches)
constexpr int kWFragN = 18 * 2 * 64 * 8; // 18432 bf16 values (36,864 B)
constexpr int kCap   = 24;               // bucket capacity; P(overflow) ~ 6e-10 at Poisson(3)

// ws layout (bytes), 16B-aligned
constexpr size_t kOffPool   = 0;                          // bf16 pooled: 28,901,376
constexpr size_t kOffWfrag  = 28901376;                   // 36,864
constexpr size_t kOffCur    = kOffWfrag + 36864;          // 112,896
constexpr size_t kOffBucket = kOffCur + 112896;           // N_UP*24*8 = 5,419,008
}

typedef __attribute__((ext_vector_type(8))) short short8;
typedef __attribute__((ext_vector_type(4))) float f32x4;

__device__ __forceinline__ unsigned short f32_to_bf16(float f) {  // RNE
    unsigned int u = __float_as_uint(f);
    u += 0x7fffu + ((u >> 16) & 1u);
    return (unsigned short)(u >> 16);
}

// --- zero cursor (graph-safe, ~1 us) --------------------------------------
__global__ __launch_bounds__(256) void zero_kernel(int* __restrict__ cursor) {
    int i = blockIdx.x * 256 + threadIdx.x;
    if (i < kNUp) cursor[i] = 0;
}

// --- merged prep: blocks [0,72) transpose W to fragment order; blocks [72,...) bucket edges
__global__ __launch_bounds__(256) void prep_kernel(const float* __restrict__ W,
                                                   unsigned short* __restrict__ wfrag,
                                                   const int* __restrict__ row,
                                                   const int* __restrict__ col,
                                                   const float* __restrict__ val,
                                                   int* __restrict__ cursor,
                                                   uint2* __restrict__ bucket) {
    int bid = blockIdx.x;
    if (bid < kWFragN / 256) {
        int i  = bid * 256 + threadIdx.x;
        int j  = i & 7;
        int l  = (i >> 3) & 63;
        int ct = (i >> 9) & 1;
        int ks = i >> 10;                            // 0..17
        int k  = ks * 32 + (l >> 4) * 8 + j;
        int o  = ct * 16 + (l & 15);
        wfrag[i] = f32_to_bf16(W[k * kCout + o]);
    } else {
        int e = (bid - kWFragN / 256) * 256 + threadIdx.x;
        if (e >= kE) return;
        int r = row[e];
        int slot = atomicAdd(&cursor[r], 1);
        if ((unsigned)slot < (unsigned)kCap)
            bucket[(size_t)r * kCap + slot] = make_uint2((unsigned)col[e], __float_as_uint(val[e]));
    }
}

// --- pooled[b,r,c] = sum_{edges of r} x[b,col,c]*val, stored bf16 ---------
// BATCH<->XCD AFFINITY: b = blockIdx&7; round-robin dispatch pins each batch's
// blocks to one XCD, so the per-XCD x working set is one 1.8 MB batch slice
// (< 4 MiB L2) instead of the full 14.45 MB (LLC-miss path). The 173 MB of
// logical x reads become L2 hits. thread = (r, c4), one batch, f32x4 loads;
// TLP from high occupancy (~24 VGPR) replaces the old per-thread ILP.
__global__ __launch_bounds__(256) void pool_gather(const float* __restrict__ x,
                                                   const int* __restrict__ cursor,
                                                   const uint2* __restrict__ bucket,
                                                   unsigned short* __restrict__ poolb) {
    int t  = threadIdx.x;
    int c4 = t & 15;                                 // float4 chunk within row
    int b  = blockIdx.x & 7;                         // batch -> XCD (round-robin)
    int rb = blockIdx.x >> 3;                        // row-block 0..1763
    int r  = rb * 16 + (t >> 4);                     // < N_UP
    int n  = min(cursor[r], kCap);
    const uint2* bk = bucket + (size_t)r * kCap;
    const float* xb = x + (size_t)b * kNIn * kCin + (size_t)c4 * 4;

    f32x4 acc = {0.f, 0.f, 0.f, 0.f};

#pragma unroll
    for (int p = 0; p < 4; ++p) {                    // pairs (0,1),(2,3),(4,5),(6,7)
        if (2 * p < n) {
            uint4 q = *reinterpret_cast<const uint4*>(bk + 2 * p);
            unsigned c0 = min(q.x, (unsigned)(kNIn - 1));
            float    v0 = __uint_as_float(q.y);
            unsigned c1 = min(q.z, (unsigned)(kNIn - 1));
            float    v1 = (2 * p + 1 < n) ? __uint_as_float(q.w) : 0.f;
            f32x4 xv0 = *reinterpret_cast<const f32x4*>(xb + (size_t)c0 * kCin);
            f32x4 xv1 = *reinterpret_cast<const f32x4*>(xb + (size_t)c1 * kCin);
#pragma unroll
            for (int j = 0; j < 4; ++j)
                acc[j] = fmaf(xv1[j], v1, fmaf(xv0[j], v0, acc[j]));
        }
    }
    for (int k = 8; k < n; ++k) {                    // rare tail (P ~ 0.4%)
        uint2 ev = bk[k];
        float v = __uint_as_float(ev.y);
        f32x4 xv = *reinterpret_cast<const f32x4*>(xb + (size_t)ev.x * kCin);
#pragma unroll
        for (int j = 0; j < 4; ++j)
            acc[j] = fmaf(xv[j], v, acc[j]);
    }

    ushort4 o;
    o.x = f32_to_bf16(acc[0]);
    o.y = f32_to_bf16(acc[1]);
    o.z = f32_to_bf16(acc[2]);
    o.w = f32_to_bf16(acc[3]);
    *reinterpret_cast<ushort4*>(poolb + ((size_t)b * kNUp + r) * kCin + c4 * 4) = o;
}

// --- MFMA GEMM: out[R,o] = relu(sum_f spiral[R,f]*W[f,o] + bias[o]) -------
// 4 waves/block, 1 16-row M-tile per wave. W fragments staged in LDS (36,864 B,
// 4 blocks/CU). All 9 idx + 18 A-fragment loads issued BEFORE __syncthreads():
// barrier fence keeps them hoisted, vmcnt-drain hides latency under LDS fill.
// XCD chunk swizzle: 441 consecutive work-ids = one batch (3.6 MB < 4 MiB L2/XCD).
__global__ __launch_bounds__(256) void gemm_mfma(const unsigned short* __restrict__ poolb,
                                                 const unsigned short* __restrict__ wfrag,
                                                 const float* __restrict__ bias,
                                                 const int* __restrict__ indices,
                                                 float* __restrict__ out) {
    __shared__ short8 Bs[18 * 2 * 64];               // 2304 short8 = 36,864 B
    int t = threadIdx.x;
    const short8* wf = (const short8*)wfrag;
#pragma unroll
    for (int i = 0; i < 9; ++i)                      // coalesced b128 fill
        Bs[i * 256 + t] = wf[i * 256 + t];

    int l = t & 63;
    int w = t >> 6;
    int bid = blockIdx.x;
    int wk = (bid & 7) * (gridDim.x >> 3) + (bid >> 3);  // grid 3528 = 8*441
    int mtile = wk * 4 + w;
    int m  = l & 15;
    int kg = l >> 4;
    int b  = mtile / kTilesPerB;
    int nn = (mtile - b * kTilesPerB) * 16 + m;
    const unsigned short* pb = poolb + (size_t)b * kNUp * kCin;

    int idxs[kSeq];
#pragma unroll
    for (int s = 0; s < kSeq; ++s) idxs[s] = indices[nn * kSeq + s];

    short8 A0[kSeq], A1[kSeq];
#pragma unroll
    for (int s = 0; s < kSeq; ++s) {
        const short8* arow = (const short8*)(pb + (size_t)idxs[s] * kCin);
        A0[s] = arow[kg];                            // channels 0..31, this lane's 16B
        A1[s] = arow[4 + kg];                        // channels 32..63
    }
    float bs0 = bias[m];
    float bs1 = bias[16 + m];

    __syncthreads();                                 // Bs ready; A loads drained here

    f32x4 acc0 = {0.f, 0.f, 0.f, 0.f};
    f32x4 acc1 = {0.f, 0.f, 0.f, 0.f};
#pragma unroll
    for (int s = 0; s < kSeq; ++s) {
        short8 b00 = Bs[((s * 2 + 0) * 2 + 0) * 64 + l];
        short8 b01 = Bs[((s * 2 + 0) * 2 + 1) * 64 + l];
        short8 b10 = Bs[((s * 2 + 1) * 2 + 0) * 64 + l];
        short8 b11 = Bs[((s * 2 + 1) * 2 + 1) * 64 + l];
        acc0 = __builtin_amdgcn_mfma_f32_16x16x32_bf16(A0[s], b00, acc0, 0, 0, 0);
        acc1 = __builtin_amdgcn_mfma_f32_16x16x32_bf16(A0[s], b01, acc1, 0, 0, 0);
        acc0 = __builtin_amdgcn_mfma_f32_16x16x32_bf16(A1[s], b10, acc0, 0, 0, 0);
        acc1 = __builtin_amdgcn_mfma_f32_16x16x32_bf16(A1[s], b11, acc1, 0, 0, 0);
    }

    int orow0 = mtile * 16 + kg * 4;
#pragma unroll
    for (int r = 0; r < 4; ++r) {
        size_t orow = (size_t)(orow0 + r) * kCout;
        out[orow + m]      = fmaxf(acc0[r] + bs0, 0.f);
        out[orow + 16 + m] = fmaxf(acc1[r] + bs1, 0.f);
    }
}

extern "C" void kernel_launch(void* const* d_in, const int* in_sizes, int n_in,
                              void* d_out, int out_size, void* d_ws, size_t ws_size,
                              hipStream_t stream) {
    const float* x    = (const float*)d_in[0];
    const float* val  = (const float*)d_in[1];
    const float* W    = (const float*)d_in[2];
    const float* bias = (const float*)d_in[3];
    const int* row     = (const int*)d_in[4];
    const int* col     = (const int*)d_in[5];
    const int* indices = (const int*)d_in[6];
    float* out = (float*)d_out;

    char* wsb = (char*)d_ws;
    unsigned short* poolb = (unsigned short*)(wsb + kOffPool);
    unsigned short* wfrag = (unsigned short*)(wsb + kOffWfrag);
    int* cursor  = (int*)(wsb + kOffCur);
    uint2* bucket = (uint2*)(wsb + kOffBucket);

    zero_kernel<<<(kNUp + 255) / 256, 256, 0, stream>>>(cursor);

    constexpr int prep_blocks = kWFragN / 256 + (kE + 255) / 256;  // 72 + 331
    prep_kernel<<<prep_blocks, 256, 0, stream>>>(W, wfrag, row, col, val, cursor, bucket);

    pool_gather<<<kNUp / 16 * kB, 256, 0, stream>>>(x, cursor, bucket, poolb);

    gemm_mfma<<<(kMRows / 16) / 4, 256, 0, stream>>>(poolb, wfrag, bias, indices, out);
}